// Round 12
// baseline (396.235 us; speedup 1.0000x reference)
//
#include <hip/hip_runtime.h>

// ---------------- problem constants ----------------
#define HID   2048
#define NHEAD 16
#define HD    128
#define SEQ   2048
#define BATCH 2
#define MROWS (BATCH*SEQ)        // 4096
#define NQKV  (3*HID)            // 6144
#define INV_NORM 0.08838834764831845f
#define LOG2E    1.4426950408889634f
#define SCALE_L2 (INV_NORM*LOG2E)

typedef __attribute__((ext_vector_type(8)))  __bf16 bf16x8;
typedef __attribute__((ext_vector_type(4)))  float  f32x4;
typedef __attribute__((ext_vector_type(16))) float  f32x16;

typedef __attribute__((address_space(1))) void GV;
typedef __attribute__((address_space(3))) void LV;

__device__ __forceinline__ void async16(const void* g, void* l) {
  __builtin_amdgcn_global_load_lds((const GV*)g, (LV*)l, 16, 0, 0);
}

__device__ __forceinline__ unsigned short f2bf(float f) {
  unsigned u = __builtin_bit_cast(unsigned, f);
  u += 0x7FFFu + ((u >> 16) & 1u);       // RNE
  return (unsigned short)(u >> 16);
}

__device__ __forceinline__ unsigned pkbf(float a, float b) {
#if __has_builtin(__builtin_amdgcn_cvt_pk_bf16_f32)
  typedef __attribute__((ext_vector_type(2))) __bf16 bf16x2;
  bf16x2 r = __builtin_amdgcn_cvt_pk_bf16_f32(a, b);
  return __builtin_bit_cast(unsigned, r);
#else
  return (unsigned)f2bf(a) | ((unsigned)f2bf(b) << 16);
#endif
}

// exchange a's upper 32 lanes with b's lower 32 lanes (v_permlane32_swap_b32 a, b)
__device__ __forceinline__ void pl32swap(unsigned &a, unsigned &b) {
#if __has_builtin(__builtin_amdgcn_permlane32_swap)
  typedef __attribute__((ext_vector_type(2))) unsigned u32x2;
  u32x2 r = __builtin_amdgcn_permlane32_swap(a, b, false, false);
  a = r[0]; b = r[1];
#else
  asm volatile("v_permlane32_swap_b32 %0, %1" : "+v"(a), "+v"(b));
#endif
}

__device__ __forceinline__ void mfma16(f32x4& c, bf16x8 a, bf16x8 b) {
  c = __builtin_amdgcn_mfma_f32_16x16x32_bf16(a, b, c, 0, 0, 0);
}

// LDS fragment read with chunk-XOR swizzle (BK=64 -> 8 chunks of 16B per row)
__device__ __forceinline__ bf16x8 frag(const unsigned short* buf, int row, int chunk) {
  return *(const bf16x8*)(buf + ((row * 8 + (chunk ^ (row & 7))) << 3));
}

// ---------------- fp32 -> bf16 cast, flat exact grid (no empty blocks) ----------------
__global__ __launch_bounds__(256) void cvt_all_kernel(
    const float* __restrict__ hidden,
    const float* __restrict__ W0, const float* __restrict__ W1,
    const float* __restrict__ W2, const float* __restrict__ W3,
    unsigned short* __restrict__ Xb) {
  size_t e = ((size_t)blockIdx.x * 256 + threadIdx.x) * 4;
  const float* src;
  if (e < (size_t)MROWS * HID) {
    src = hidden + e;
  } else {
    size_t r = e - (size_t)MROWS * HID;
    int sel = (int)(r >> 22);                 // HID*HID = 2^22
    size_t off = r & ((1u << 22) - 1);
    src = ((sel == 0) ? W0 : (sel == 1) ? W1 : (sel == 2) ? W2 : W3) + off;
  }
  float4 v = *(const float4*)src;
  ushort4 o;
  o.x = f2bf(v.x); o.y = f2bf(v.y); o.z = f2bf(v.z); o.w = f2bf(v.w);
  *(ushort4*)(Xb + e) = o;
}

// ---------------- GEMM 1: QKV projection, persistent 256-block, 3x(256x128) passes ----
// R12: merged full-tile phases — 1 phase per K-tile (16 ds_read -> 32 MFMA -> one
// lgkm(0)/vmcnt/barrier). 96 phases/block (was 192); per-phase fixed overhead
// (barrier skew + drains) amortized over 2x MFMA. Tri-buffer FIFO: phase t computes
// buf(t%3), stages tile t+2 -> buf((t+2)%3) (dead since phase t-1); end vmcnt(6)
// drains tile t+1's 6 loads (issued one full phase earlier).
#define BUFU (24576)   // ushorts per buffer (48KB): A 16384 + B 8192
#define BUF3 (3 * BUFU)

__global__ __launch_bounds__(512, 2) void gemm_qkv384_kernel(
    const unsigned short* __restrict__ Xb, const unsigned short* __restrict__ Wb,
    const float* __restrict__ bq, const float* __restrict__ bk,
    const float* __restrict__ bv, unsigned short* __restrict__ Cout,
    unsigned short* __restrict__ Vt) {
  __shared__ __align__(16) unsigned short smem[BUF3];   // 144 KiB

  const int tid  = threadIdx.x;
  const int w    = tid >> 6;
  const int lane = tid & 63;
  const int l16  = lane & 15;
  const int quad = lane >> 4;
  const int wm   = (w & 3) * 64;    // 4 M-waves
  const int wn   = (w >> 2) * 64;   // 2 N-waves

  const int wg = blockIdx.x;
  const int sw = (wg & 7) * 32 + (wg >> 3);
  const int m0  = (sw & 15) * 256;
  const int rn0 = (sw >> 4) * 384;

  const int sr  = tid >> 3;
  const int scs = ((tid & 7) ^ (sr & 7)) * 8;
  const unsigned short* aBase = Xb + (size_t)(m0 + sr) * HID + scs;

#define STGA(UB, RB, KT)                                              \
  async16(aBase + (size_t)(RB) * HID + (KT),                          \
          (char*)smem + (UB) * 2 + (RB) * 128 + w * 1024)
#define STGB(UB, RB, KT)                                              \
  async16(bBase + (size_t)(RB) * HID + (KT),                          \
          (char*)smem + (UB) * 2 + 32768 + (RB) * 128 + w * 1024)

#define STG6(UB, KT)                                                  \
  { STGA(UB, 0, KT); STGA(UB, 64, KT); STGA(UB, 128, KT);             \
    STGA(UB, 192, KT); STGB(UB, 0, KT); STGB(UB, 64, KT); }

#define VM6  asm volatile("s_waitcnt vmcnt(6)" ::: "memory")
#define VM0  asm volatile("s_waitcnt vmcnt(0)" ::: "memory")

// full-tile phase: 16 ds_read (both kk halves) | STG | 32 MFMA | lgkm(0) | wait | barrier
#define PHASE2(UB, STGBLK, WAITBLK)                                            \
  {                                                                            \
    const unsigned short* Ab = smem + (UB);                                    \
    const unsigned short* Bb = Ab + 16384;                                     \
    bf16x8 ta0[4], tb0[4], ta1[4], tb1[4];                                     \
    _Pragma("unroll")                                                          \
    for (int ii = 0; ii < 4; ++ii) ta0[ii] = frag(Ab, wm + ii * 16 + l16, quad); \
    _Pragma("unroll")                                                          \
    for (int j = 0; j < 4; ++j)  tb0[j] = frag(Bb, wn + j * 16 + l16, quad);   \
    _Pragma("unroll")                                                          \
    for (int ii = 0; ii < 4; ++ii) ta1[ii] = frag(Ab, wm + ii * 16 + l16, 4 + quad); \
    _Pragma("unroll")                                                          \
    for (int j = 0; j < 4; ++j)  tb1[j] = frag(Bb, wn + j * 16 + l16, 4 + quad); \
    STGBLK;                                                                    \
    __builtin_amdgcn_s_setprio(1);                                             \
    _Pragma("unroll")                                                          \
    for (int ii = 0; ii < 4; ++ii)                                             \
      _Pragma("unroll")                                                        \
      for (int j = 0; j < 4; ++j) mfma16(acc[ii][j], ta0[ii], tb0[j]);         \
    _Pragma("unroll")                                                          \
    for (int ii = 0; ii < 4; ++ii)                                             \
      _Pragma("unroll")                                                        \
      for (int j = 0; j < 4; ++j) mfma16(acc[ii][j], ta1[ii], tb1[j]);         \
    __builtin_amdgcn_s_setprio(0);                                             \
    asm volatile("s_waitcnt lgkmcnt(0)" ::: "memory");                         \
    WAITBLK;                                                                   \
    __builtin_amdgcn_s_barrier();                                              \
  }

  for (int p = 0; p < 3; ++p) {
    const unsigned short* bBase = Wb + (size_t)(rn0 + p * 128 + sr) * HID + scs;

    f32x4 acc[4][4];
    const f32x4 zero = {0.f, 0.f, 0.f, 0.f};
#pragma unroll
    for (int a = 0; a < 4; ++a)
#pragma unroll
      for (int j = 0; j < 4; ++j) acc[a][j] = zero;

    // prologue: t0 -> buf0, t1 -> buf1 (6 loads each); drain t0, leave t1 in flight
    STG6(0, 0);
    STG6(BUFU, 64);
    VM6;
    __builtin_amdgcn_s_barrier();

    // main loop: 10 groups x 3 tiles (static rotation); tile t -> buffer (t%3)
    int kb = 0;   // = g * 192
    for (int g = 0; g < 10; ++g) {
      PHASE2(0,        STG6(2*BUFU, kb+128), VM6);   // t=3g:   compute buf0, stage t+2 -> buf2
      PHASE2(BUFU,     STG6(0,      kb+192), VM6);   // t=3g+1: compute buf1, stage t+2 -> buf0
      PHASE2(2*BUFU,   STG6(BUFU,   kb+256), VM6);   // t=3g+2: compute buf2, stage t+2 -> buf1
      kb += 192;
    }
    // peeled tiles 30 (buf0), 31 (buf1): no prefetch; VM0 drains tile 31's loads
    PHASE2(0,    {}, VM0);
    PHASE2(BUFU, {}, {});

    // pass epilogue: bias + bf16 store of the 256x128 column block (+ fused V-transpose)
#pragma unroll
    for (int j = 0; j < 4; ++j) {
      int ng = rn0 + p * 128 + wn + j * 16 + l16;
      float bias = (ng < HID) ? bq[ng] : (ng < 2 * HID ? bk[ng - HID] : bv[ng - 2 * HID]);
      if (Vt != nullptr && ng >= 2 * HID) {
        const int vidx = ng - 2 * HID;
        const int bb = m0 >> 11;
        unsigned short* vrow = Vt
            + ((size_t)((bb * 16 + (vidx >> 7)) * 128 + (vidx & 127))) * SEQ
            + (m0 & 2047) + wm + quad * 4;
#pragma unroll
        for (int a = 0; a < 4; ++a) {
          ushort4 pk4;
          pk4.x = f2bf(acc[a][j][0] + bias);
          pk4.y = f2bf(acc[a][j][1] + bias);
          pk4.z = f2bf(acc[a][j][2] + bias);
          pk4.w = f2bf(acc[a][j][3] + bias);
          *(ushort4*)(vrow + a * 16) = pk4;
        }
      } else {
#pragma unroll
        for (int a = 0; a < 4; ++a)
#pragma unroll
          for (int r = 0; r < 4; ++r) {
            int mg = m0 + wm + a * 16 + quad * 4 + r;
            Cout[(size_t)mg * NQKV + ng] = f2bf(acc[a][j][r] + bias);
          }
      }
    }
  }
#undef STGA
#undef STGB
#undef STG6
#undef PHASE2
#undef VM6
#undef VM0
}

// ---------------- GEMM 2: out-proj, SAME merged-phase structure (single pass) ----------------
__global__ __launch_bounds__(512, 2) void gemm_out384_kernel(
    const unsigned short* __restrict__ Ctx, const unsigned short* __restrict__ Wdb,
    const float* __restrict__ bd, const float* __restrict__ Res,
    float* __restrict__ Out) {
  __shared__ __align__(16) unsigned short smem[BUF3];   // 144 KiB

  const int tid  = threadIdx.x;
  const int w    = tid >> 6;
  const int lane = tid & 63;
  const int l16  = lane & 15;
  const int quad = lane >> 4;
  const int wm   = (w & 3) * 64;
  const int wn   = (w >> 2) * 64;

  const int wg = blockIdx.x;
  const int sw = (wg & 7) * 32 + (wg >> 3);
  const int m0  = (sw & 15) * 256;
  const int rn0 = (sw >> 4) * 128;

  const int sr  = tid >> 3;
  const int scs = ((tid & 7) ^ (sr & 7)) * 8;
  const unsigned short* aBase = Ctx + (size_t)(m0 + sr) * HID + scs;
  const unsigned short* bBase = Wdb + (size_t)(rn0 + sr) * HID + scs;

#define STGA(UB, RB, KT)                                              \
  async16(aBase + (size_t)(RB) * HID + (KT),                          \
          (char*)smem + (UB) * 2 + (RB) * 128 + w * 1024)
#define STGB(UB, RB, KT)                                              \
  async16(bBase + (size_t)(RB) * HID + (KT),                          \
          (char*)smem + (UB) * 2 + 32768 + (RB) * 128 + w * 1024)

#define STG6(UB, KT)                                                  \
  { STGA(UB, 0, KT); STGA(UB, 64, KT); STGA(UB, 128, KT);             \
    STGA(UB, 192, KT); STGB(UB, 0, KT); STGB(UB, 64, KT); }

#define VM6  asm volatile("s_waitcnt vmcnt(6)" ::: "memory")
#define VM0  asm volatile("s_waitcnt vmcnt(0)" ::: "memory")

#define PHASE2(UB, STGBLK, WAITBLK)                                            \
  {                                                                            \
    const unsigned short* Ab = smem + (UB);                                    \
    const unsigned short* Bb = Ab + 16384;                                     \
    bf16x8 ta0[4], tb0[4], ta1[4], tb1[4];                                     \
    _Pragma("unroll")                                                          \
    for (int ii = 0; ii < 4; ++ii) ta0[ii] = frag(Ab, wm + ii * 16 + l16, quad); \
    _Pragma("unroll")                                                          \
    for (int j = 0; j < 4; ++j)  tb0[j] = frag(Bb, wn + j * 16 + l16, quad);   \
    _Pragma("unroll")                                                          \
    for (int ii = 0; ii < 4; ++ii) ta1[ii] = frag(Ab, wm + ii * 16 + l16, 4 + quad); \
    _Pragma("unroll")                                                          \
    for (int j = 0; j < 4; ++j)  tb1[j] = frag(Bb, wn + j * 16 + l16, 4 + quad); \
    STGBLK;                                                                    \
    __builtin_amdgcn_s_setprio(1);                                             \
    _Pragma("unroll")                                                          \
    for (int ii = 0; ii < 4; ++ii)                                             \
      _Pragma("unroll")                                                        \
      for (int j = 0; j < 4; ++j) mfma16(acc[ii][j], ta0[ii], tb0[j]);         \
    _Pragma("unroll")                                                          \
    for (int ii = 0; ii < 4; ++ii)                                             \
      _Pragma("unroll")                                                        \
      for (int j = 0; j < 4; ++j) mfma16(acc[ii][j], ta1[ii], tb1[j]);         \
    __builtin_amdgcn_s_setprio(0);                                             \
    asm volatile("s_waitcnt lgkmcnt(0)" ::: "memory");                         \
    WAITBLK;                                                                   \
    __builtin_amdgcn_s_barrier();                                              \
  }

  f32x4 acc[4][4];
  const f32x4 zero = {0.f, 0.f, 0.f, 0.f};
#pragma unroll
  for (int a = 0; a < 4; ++a)
#pragma unroll
    for (int j = 0; j < 4; ++j) acc[a][j] = zero;

  STG6(0, 0);
  STG6(BUFU, 64);
  VM6;
  __builtin_amdgcn_s_barrier();

  int kb = 0;
  for (int g = 0; g < 10; ++g) {
    PHASE2(0,        STG6(2*BUFU, kb+128), VM6);
    PHASE2(BUFU,     STG6(0,      kb+192), VM6);
    PHASE2(2*BUFU,   STG6(BUFU,   kb+256), VM6);
    kb += 192;
  }
  PHASE2(0,    {}, VM0);
  PHASE2(BUFU, {}, {});

#pragma unroll
  for (int j = 0; j < 4; ++j) {
    int ng = rn0 + wn + j * 16 + l16;
    float bias = bd[ng];
#pragma unroll
    for (int a = 0; a < 4; ++a)
#pragma unroll
      for (int r = 0; r < 4; ++r) {
        int mg = m0 + wm + a * 16 + quad * 4 + r;
        size_t off = (size_t)mg * HID + ng;
        Out[off] = acc[a][j][r] + bias + Res[off];
      }
  }
#undef STGA
#undef STGB
#undef STG6
#undef PHASE2
#undef VM6
#undef VM0
}

// ---------------- V transpose (FALLBACK only, when ws too small for fused Vt) ----------------
__global__ __launch_bounds__(256) void vtrans_kernel(const unsigned short* __restrict__ QKV,
                                                     unsigned short* __restrict__ Vt) {
  __shared__ __align__(16) unsigned short T[64][72];
  const int s0 = blockIdx.x * 64, d0 = blockIdx.y * 64, bh = blockIdx.z;
  const int b = bh >> 4, h = bh & 15;
  const int tid = threadIdx.x;
#pragma unroll
  for (int i = 0; i < 2; ++i) {
    int idx = i * 256 + tid;
    int r = idx >> 3, ch = idx & 7;
    const unsigned short* g = QKV + ((size_t)b * SEQ + s0 + r) * NQKV + 2 * HID + h * HD + d0 + ch * 8;
    *(uint4*)(&T[r][ch * 8]) = *(const uint4*)g;
  }
  __syncthreads();
#pragma unroll
  for (int i = 0; i < 2; ++i) {
    int idx = i * 256 + tid;
    int d = idx >> 3, ch = idx & 7;
    unsigned short v[8];
#pragma unroll
    for (int x = 0; x < 8; ++x) v[x] = T[ch * 8 + x][d];
    unsigned short* g = Vt + ((size_t)bh * HD + d0 + d) * SEQ + s0 + ch * 8;
    *(uint4*)g = *(const uint4*)v;
  }
}

// ---------------- flash attention: 8-wave block, shared K/V staging (R11, unchanged) ----------------
__global__ __launch_bounds__(512, 2) void attn_kernel(
    const unsigned short* __restrict__ QKV, const unsigned short* __restrict__ Vt,
    const float* __restrict__ alibi, unsigned short* __restrict__ Ctx) {
  __shared__ __align__(16) char smem[73728];
  unsigned short* Ks0  = (unsigned short*)smem;
  unsigned short* Ks1  = (unsigned short*)(smem + 16384);
  unsigned short* Vts0 = (unsigned short*)(smem + 32768);
  unsigned short* Vts1 = (unsigned short*)(smem + 49152);
  float*          Alsf = (float*)(smem + 65536);
  unsigned short* Qs   = (unsigned short*)smem;   // alias: Q staging (64 KB over all 4 bufs)

  const int tid = threadIdx.x, w = tid >> 6, lane = tid & 63;
  const int l32 = lane & 31, h = lane >> 5;
  const int bid = blockIdx.x;
  const int t  = bid >> 3;
  const int q0 = (t & 7) * 256;
  const int bh = (bid & 7) + 8 * (t >> 3);
  const int b = bh >> 4, hh = bh & 15;
  const size_t rowbase = (size_t)b * SEQ;
  const float* ali = alibi + (size_t)bh * SEQ;
  const unsigned short* Vbh = Vt + (size_t)bh * HD * SEQ;

  {
    const unsigned short* qbase = QKV + (rowbase + q0) * NQKV + hh * HD;
#pragma unroll
    for (int i = 0; i < 8; ++i) {
      int slot = i * 512 + w * 64 + lane;
      int r = slot >> 4, c = (slot & 15) ^ (r & 15);
      async16(qbase + (size_t)r * NQKV + c * 8, (char*)Qs + (size_t)(i * 512 + w * 64) * 16);
    }
    async16((const char*)ali + (size_t)(w * 64 + lane) * 16, (char*)Alsf + (size_t)(w * 64) * 16);
  }
  __syncthreads();
  bf16x8 qf[8];
  {
    int qr = w * 32 + l32;
#pragma unroll
    for (int ks = 0; ks < 8; ++ks) {
      int c = (ks * 2 + h) ^ (qr & 15);
      qf[ks] = *(const bf16x8*)(Qs + (qr * 16 + c) * 8);
    }
  }

  f32x16 oacc[4];
  float l_acc = 0.f;
#pragma unroll
  for (int nb = 0; nb < 4; ++nb)
#pragma unroll
    for (int r = 0; r < 16; ++r) oacc[nb][r] = 0.f;

  __syncthreads();

#define STAGE_K(T, KD)                                                           \
  {                                                                              \
    const unsigned short* kbase = QKV + (rowbase + (size_t)(T) * 64) * NQKV + HID + hh * HD; \
    _Pragma("unroll")                                                            \
    for (int i = 0; i < 2; ++i) {                                                \
      int slot = i * 512 + w * 64 + lane;                                        \
      int r = slot >> 4, c = (slot & 15) ^ (r & 15);                             \
      async16(kbase + (size_t)r * NQKV + c * 8, (char*)(KD) + (size_t)(i * 512 + w * 64) * 16); \
    }                                                                            \
  }
#define STAGE_V(T, VD)                                                           \
  {                                                                              \
    const unsigned short* vbase = Vbh + (T) * 64;                                \
    _Pragma("unroll")                                                            \
    for (int i = 0; i < 2; ++i) {                                                \
      int slot = i * 512 + w * 64 + lane;                                        \
      int r = slot >> 3, c = (slot & 7) ^ (r & 7);                               \
      async16(vbase + (size_t)r * SEQ + c * 8, (char*)(VD) + (size_t)(i * 512 + w * 64) * 16); \
    }                                                                            \
  }

#define QKT(SACC, KBUF)                                                          \
  {                                                                              \
    _Pragma("unroll")                                                            \
    for (int mb = 0; mb < 2; ++mb)                                               \
      _Pragma("unroll")                                                          \
      for (int r = 0; r < 16; ++r) (SACC)[mb][r] = 0.f;                          \
    __builtin_amdgcn_s_setprio(1);                                               \
    _Pragma("unroll")                                                            \
    for (int ks = 0; ks < 8; ++ks)                                               \
      _Pragma("unroll")                                                          \
      for (int mb = 0; mb < 2; ++mb) {                                           \
        bf16x8 kf = *(const bf16x8*)((KBUF) + ((mb * 32 + l32) * 16 + ((ks * 2 + h) ^ (l32 & 15))) * 8); \
        (SACC)[mb] = __builtin_amdgcn_mfma_f32_32x32x16_bf16(kf, qf[ks], (SACC)[mb], 0, 0, 0); \
      }                                                                          \
    __builtin_amdgcn_s_setprio(0);                                               \
  }

#define SOFTMAX(SACC, KT, PFR)                                                   \
  {                                                                              \
    const float* alsk = Alsf + (KT) * 64 + 4 * h;                                \
    _Pragma("unroll")                                                            \
    for (int mb = 0; mb < 2; ++mb) {                                             \
      float p[16];                                                               \
      _Pragma("unroll")                                                          \
      for (int g = 0; g < 4; ++g) {                                              \
        float4 av = *(const float4*)(alsk + mb * 32 + g * 8);                    \
        p[g * 4 + 0] = __builtin_amdgcn_exp2f((SACC)[mb][g * 4 + 0] * SCALE_L2 + av.x * LOG2E); \
        p[g * 4 + 1] = __builtin_amdgcn_exp2f((SACC)[mb][g * 4 + 1] * SCALE_L2 + av.y * LOG2E); \
        p[g * 4 + 2] = __builtin_amdgcn_exp2f((SACC)[mb][g * 4 + 2] * SCALE_L2 + av.z * LOG2E); \
        p[g * 4 + 3] = __builtin_amdgcn_exp2f((SACC)[mb][g * 4 + 3] * SCALE_L2 + av.w * LOG2E); \
        l_acc += (p[g * 4 + 0] + p[g * 4 + 1]) + (p[g * 4 + 2] + p[g * 4 + 3]);  \
      }                                                                          \
      unsigned c0 = pkbf(p[0],  p[1]),  c1 = pkbf(p[2],  p[3]);                  \
      unsigned c2 = pkbf(p[4],  p[5]),  c3 = pkbf(p[6],  p[7]);                  \
      unsigned c4 = pkbf(p[8],  p[9]),  c5 = pkbf(p[10], p[11]);                 \
      unsigned c6 = pkbf(p[12], p[13]), c7 = pkbf(p[14], p[15]);                 \
      pl32swap(c0, c2);  pl32swap(c1, c3);                                       \
      pl32swap(c4, c6);  pl32swap(c5, c7);                                       \
      uint4 f0; f0.x = c0; f0.y = c1; f0.z = c2; f0.w = c3;                      \
      uint4 f1; f1.x = c4; f1.y = c5; f1.z = c6; f1.w = c7;                      \
      (PFR)[mb * 2 + 0] = __builtin_bit_cast(bf16x8, f0);                        \
      (PFR)[mb * 2 + 1] = __builtin_bit_cast(bf16x8, f1);                        \
    }                                                                            \
  }

#define PVOP(PFR, VBUF)                                                          \
  {                                                                              \
    __builtin_amdgcn_s_setprio(1);                                               \
    _Pragma("unroll")                                                            \
    for (int ks2 = 0; ks2 < 4; ++ks2) {                                          \
      bf16x8 pf = (PFR)[ks2];                                                    \
      _Pragma("unroll")                                                          \
      for (int nb = 0; nb < 4; ++nb) {                                           \
        bf16x8 vf = *(const bf16x8*)((VBUF) + ((nb * 32 + l32) * 8 + ((ks2 * 2 + h) ^ (l32 & 7))) * 8); \
        oacc[nb] = __builtin_amdgcn_mfma_f32_32x32x16_bf16(pf, vf, oacc[nb], 0, 0, 0); \
      }                                                                          \
    }                                                                            \
    __builtin_amdgcn_s_setprio(0);                                               \
  }

  STAGE_K(0, Ks0);  STAGE_V(0, Vts0);
  STAGE_K(1, Ks1);  STAGE_V(1, Vts1);
  asm volatile("s_waitcnt vmcnt(4)" ::: "memory");
  __builtin_amdgcn_s_barrier();

  f32x16 sA[2], sB[2];
  QKT(sA, Ks0);
  asm volatile("s_waitcnt lgkmcnt(0)" ::: "memory");
  __builtin_amdgcn_s_barrier();

  for (int kt = 0; kt < 30; kt += 2) {
    STAGE_K(kt + 2, Ks0);
    asm volatile("s_waitcnt vmcnt(4)" ::: "memory");
    QKT(sB, Ks1);
    { bf16x8 pfr[4]; SOFTMAX(sA, kt, pfr); PVOP(pfr, Vts0); }
    asm volatile("s_waitcnt lgkmcnt(0)" ::: "memory");
    __builtin_amdgcn_s_barrier();
    STAGE_V(kt + 2, Vts0);
    STAGE_K(kt + 3, Ks1);
    asm volatile("s_waitcnt vmcnt(4)" ::: "memory");
    QKT(sA, Ks0);
    { bf16x8 pfr[4]; SOFTMAX(sB, kt + 1, pfr); PVOP(pfr, Vts1); }
    asm volatile("s_waitcnt lgkmcnt(0)" ::: "memory");
    __builtin_amdgcn_s_barrier();
    STAGE_V(kt + 3, Vts1);
  }

  asm volatile("s_waitcnt vmcnt(2)" ::: "memory");
  QKT(sB, Ks1);
  { bf16x8 pfr[4]; SOFTMAX(sA, 30, pfr); PVOP(pfr, Vts0); }
  asm volatile("s_waitcnt lgkmcnt(0) vmcnt(0)" ::: "memory");
  __builtin_amdgcn_s_barrier();
  { bf16x8 pfr[4]; SOFTMAX(sB, 31, pfr); PVOP(pfr, Vts1); }
  asm volatile("s_waitcnt lgkmcnt(0)" ::: "memory");

#undef STAGE_K
#undef STAGE_V
#undef QKT
#undef SOFTMAX
#undef PVOP

  float lf = l_acc + __shfl_xor(l_acc, 32, 64);
  float rinv[16];
#pragma unroll
  for (int reg = 0; reg < 16; ++reg) {
    int row = (reg & 3) + 8 * (reg >> 2) + 4 * h;
    rinv[reg] = 1.0f / __shfl(lf, row, 64);
  }

#pragma unroll
  for (int nb = 0; nb < 4; ++nb)
#pragma unroll
    for (int reg = 0; reg < 16; ++reg) {
      int row = (reg & 3) + 8 * (reg >> 2) + 4 * h;
      size_t qg = rowbase + q0 + w * 32 + row;
      Ctx[qg * HID + hh * HD + nb * 32 + l32] = f2bf(oacc[nb][reg] * rinv[reg]);
    }
}

// ---------------- launch ----------------
extern "C" void kernel_launch(void* const* d_in, const int* in_sizes, int n_in,
                              void* d_out, int out_size, void* d_ws, size_t ws_size,
                              hipStream_t stream) {
  const float* hidden   = (const float*)d_in[0];
  const float* residual = (const float*)d_in[1];
  const float* alibi    = (const float*)d_in[2];
  const float* Wq = (const float*)d_in[3];
  const float* bq = (const float*)d_in[4];
  const float* Wk = (const float*)d_in[5];
  const float* bk = (const float*)d_in[6];
  const float* Wv = (const float*)d_in[7];
  const float* bv = (const float*)d_in[8];
  const float* Wd = (const float*)d_in[9];
  const float* bd = (const float*)d_in[10];
  float* out = (float*)d_out;

  unsigned short* Xb    = (unsigned short*)d_ws;                    // 4096*2048
  unsigned short* Wqkvb = Xb + (size_t)MROWS * HID;                 // 6144*2048
  unsigned short* Wdb   = Wqkvb + (size_t)NQKV * HID;               // 2048*2048
  unsigned short* QKVb  = Wdb + (size_t)HID * HID;                  // 4096*6144
  unsigned short* Ctxb  = QKVb + (size_t)MROWS * NQKV;              // 4096*2048
  unsigned short* VtF   = Ctxb + (size_t)MROWS * HID;               // 32*128*2048 (fused path)

  const size_t needU = (size_t)MROWS * HID + (size_t)NQKV * HID + (size_t)HID * HID
                     + (size_t)MROWS * NQKV + (size_t)MROWS * HID
                     + (size_t)BATCH * NHEAD * HD * SEQ;
  const bool fused = ws_size >= needU * sizeof(unsigned short);

  const int nTot = (MROWS * HID + 4 * HID * HID) / 4 / 256;   // 24576 blocks, exact
  cvt_all_kernel<<<nTot, 256, 0, stream>>>(hidden, Wq, Wk, Wv, Wd, Xb);

  if (fused) {
    gemm_qkv384_kernel<<<256, 512, 0, stream>>>(Xb, Wqkvb, bq, bk, bv, QKVb, VtF);
    attn_kernel<<<256, 512, 0, stream>>>(QKVb, VtF, alibi, Ctxb);
  } else {
    unsigned short* Vtb = Wqkvb;   // weights dead after gemm_qkv in this path
    gemm_qkv384_kernel<<<256, 512, 0, stream>>>(Xb, Wqkvb, bq, bk, bv, QKVb, nullptr);
    vtrans_kernel<<<dim3(SEQ / 64, HD / 64, BATCH * NHEAD), 256, 0, stream>>>(QKVb, Vtb);
    attn_kernel<<<256, 512, 0, stream>>>(QKVb, Vtb, alibi, Ctxb);
  }
  gemm_out384_kernel<<<256, 512, 0, stream>>>(Ctxb, Wdb, bd, residual, out);
}

// Round 13
// 392.750 us; speedup vs baseline: 1.0089x; 1.0089x over previous
//
#include <hip/hip_runtime.h>

// ---------------- problem constants ----------------
#define HID   2048
#define NHEAD 16
#define HD    128
#define SEQ   2048
#define BATCH 2
#define MROWS (BATCH*SEQ)        // 4096
#define NQKV  (3*HID)            // 6144
#define INV_NORM 0.08838834764831845f
#define LOG2E    1.4426950408889634f
#define SCALE_L2 (INV_NORM*LOG2E)

typedef __attribute__((ext_vector_type(8)))  __bf16 bf16x8;
typedef __attribute__((ext_vector_type(4)))  float  f32x4;
typedef __attribute__((ext_vector_type(16))) float  f32x16;

typedef __attribute__((address_space(1))) void GV;
typedef __attribute__((address_space(3))) void LV;

__device__ __forceinline__ void async16(const void* g, void* l) {
  __builtin_amdgcn_global_load_lds((const GV*)g, (LV*)l, 16, 0, 0);
}

__device__ __forceinline__ unsigned short f2bf(float f) {
  unsigned u = __builtin_bit_cast(unsigned, f);
  u += 0x7FFFu + ((u >> 16) & 1u);       // RNE
  return (unsigned short)(u >> 16);
}

__device__ __forceinline__ unsigned pkbf(float a, float b) {
#if __has_builtin(__builtin_amdgcn_cvt_pk_bf16_f32)
  typedef __attribute__((ext_vector_type(2))) __bf16 bf16x2;
  bf16x2 r = __builtin_amdgcn_cvt_pk_bf16_f32(a, b);
  return __builtin_bit_cast(unsigned, r);
#else
  return (unsigned)f2bf(a) | ((unsigned)f2bf(b) << 16);
#endif
}

// exchange a's upper 32 lanes with b's lower 32 lanes (v_permlane32_swap_b32 a, b)
__device__ __forceinline__ void pl32swap(unsigned &a, unsigned &b) {
#if __has_builtin(__builtin_amdgcn_permlane32_swap)
  typedef __attribute__((ext_vector_type(2))) unsigned u32x2;
  u32x2 r = __builtin_amdgcn_permlane32_swap(a, b, false, false);
  a = r[0]; b = r[1];
#else
  asm volatile("v_permlane32_swap_b32 %0, %1" : "+v"(a), "+v"(b));
#endif
}

__device__ __forceinline__ void mfma16(f32x4& c, bf16x8 a, bf16x8 b) {
  c = __builtin_amdgcn_mfma_f32_16x16x32_bf16(a, b, c, 0, 0, 0);
}

// LDS fragment read with chunk-XOR swizzle (BK=64 -> 8 chunks of 16B per row)
__device__ __forceinline__ bf16x8 frag(const unsigned short* buf, int row, int chunk) {
  return *(const bf16x8*)(buf + ((row * 8 + (chunk ^ (row & 7))) << 3));
}

// ---------------- fp32 -> bf16 cast, flat exact grid (no empty blocks) ----------------
__global__ __launch_bounds__(256) void cvt_all_kernel(
    const float* __restrict__ hidden,
    const float* __restrict__ W0, const float* __restrict__ W1,
    const float* __restrict__ W2, const float* __restrict__ W3,
    unsigned short* __restrict__ Xb) {
  size_t e = ((size_t)blockIdx.x * 256 + threadIdx.x) * 4;
  const float* src;
  if (e < (size_t)MROWS * HID) {
    src = hidden + e;
  } else {
    size_t r = e - (size_t)MROWS * HID;
    int sel = (int)(r >> 22);                 // HID*HID = 2^22
    size_t off = r & ((1u << 22) - 1);
    src = ((sel == 0) ? W0 : (sel == 1) ? W1 : (sel == 2) ? W2 : W3) + off;
  }
  float4 v = *(const float4*)src;
  ushort4 o;
  o.x = f2bf(v.x); o.y = f2bf(v.y); o.z = f2bf(v.z); o.w = f2bf(v.w);
  *(ushort4*)(Xb + e) = o;
}

// ---------------- GEMM 1: QKV projection, persistent 256-block, 3x(256x128) passes ----
// (R11 structure: split-phase, static rotation, 1 barrier/phase, vmcnt(6) FIFO;
//  fused V-transpose epilogue.)
#define BUFU (24576)   // ushorts per buffer (48KB): A 16384 + B 8192
#define BUF3 (3 * BUFU)

__global__ __launch_bounds__(512, 2) void gemm_qkv384_kernel(
    const unsigned short* __restrict__ Xb, const unsigned short* __restrict__ Wb,
    const float* __restrict__ bq, const float* __restrict__ bk,
    const float* __restrict__ bv, unsigned short* __restrict__ Cout,
    unsigned short* __restrict__ Vt) {
  __shared__ __align__(16) unsigned short smem[BUF3];   // 144 KiB

  const int tid  = threadIdx.x;
  const int w    = tid >> 6;
  const int lane = tid & 63;
  const int l16  = lane & 15;
  const int quad = lane >> 4;
  const int wm   = (w & 3) * 64;    // 4 M-waves
  const int wn   = (w >> 2) * 64;   // 2 N-waves

  const int wg = blockIdx.x;
  const int sw = (wg & 7) * 32 + (wg >> 3);
  const int m0  = (sw & 15) * 256;
  const int rn0 = (sw >> 4) * 384;

  const int sr  = tid >> 3;
  const int scs = ((tid & 7) ^ (sr & 7)) * 8;
  const unsigned short* aBase = Xb + (size_t)(m0 + sr) * HID + scs;

#define STGA(UB, RB, KT)                                              \
  async16(aBase + (size_t)(RB) * HID + (KT),                          \
          (char*)smem + (UB) * 2 + (RB) * 128 + w * 1024)
#define STGB(UB, RB, KT)                                              \
  async16(bBase + (size_t)(RB) * HID + (KT),                          \
          (char*)smem + (UB) * 2 + 32768 + (RB) * 128 + w * 1024)

#define VM6  asm volatile("s_waitcnt vmcnt(6)" ::: "memory")
#define VM0  asm volatile("s_waitcnt vmcnt(0)" ::: "memory")

#define PHASE(UB, KK, STGBLK, WAITBLK)                                         \
  {                                                                            \
    const unsigned short* Ab = smem + (UB);                                    \
    const unsigned short* Bb = Ab + 16384;                                     \
    bf16x8 ta[4], tb[4];                                                       \
    ta[0] = frag(Ab, wm + l16, (KK) * 4 + quad);                               \
    _Pragma("unroll")                                                          \
    for (int j = 0; j < 4; ++j)  tb[j] = frag(Bb, wn + j * 16 + l16, (KK) * 4 + quad); \
    _Pragma("unroll")                                                          \
    for (int ii = 1; ii < 4; ++ii) ta[ii] = frag(Ab, wm + ii * 16 + l16, (KK) * 4 + quad); \
    STGBLK;                                                                    \
    __builtin_amdgcn_s_setprio(1);                                             \
    _Pragma("unroll")                                                          \
    for (int ii = 0; ii < 4; ++ii)                                             \
      _Pragma("unroll")                                                        \
      for (int j = 0; j < 4; ++j) mfma16(acc[ii][j], ta[ii], tb[j]);           \
    __builtin_amdgcn_s_setprio(0);                                             \
    asm volatile("s_waitcnt lgkmcnt(0)" ::: "memory");                         \
    WAITBLK;                                                                   \
    __builtin_amdgcn_s_barrier();                                              \
  }

  for (int p = 0; p < 3; ++p) {
    const unsigned short* bBase = Wb + (size_t)(rn0 + p * 128 + sr) * HID + scs;

    f32x4 acc[4][4];
    const f32x4 zero = {0.f, 0.f, 0.f, 0.f};
#pragma unroll
    for (int a = 0; a < 4; ++a)
#pragma unroll
      for (int j = 0; j < 4; ++j) acc[a][j] = zero;

    STGA(0, 0, 0);  STGA(0, 64, 0);  STGA(0, 128, 0);  STGA(0, 192, 0);
    STGB(0, 0, 0);  STGB(0, 64, 0);
    STGA(BUFU, 0, 64);  STGA(BUFU, 64, 64);  STGA(BUFU, 128, 64);  STGA(BUFU, 192, 64);
    STGB(BUFU, 0, 64);  STGB(BUFU, 64, 64);
    VM6;
    __builtin_amdgcn_s_barrier();

    int kb = 0;
    for (int g = 0; g < 5; ++g) {
      PHASE(0,        0, { STGA(2*BUFU, 0, kb+128); STGA(2*BUFU, 64, kb+128); STGA(2*BUFU, 128, kb+128); }, {});
      PHASE(0,        1, { STGA(2*BUFU, 192, kb+128); STGB(2*BUFU, 0, kb+128); STGB(2*BUFU, 64, kb+128); }, VM6);
      PHASE(BUFU,     0, { STGA(0, 0, kb+192); STGA(0, 64, kb+192); STGA(0, 128, kb+192); }, {});
      PHASE(BUFU,     1, { STGA(0, 192, kb+192); STGB(0, 0, kb+192); STGB(0, 64, kb+192); }, VM6);
      PHASE(2*BUFU,   0, { STGA(BUFU, 0, kb+256); STGA(BUFU, 64, kb+256); STGA(BUFU, 128, kb+256); }, {});
      PHASE(2*BUFU,   1, { STGA(BUFU, 192, kb+256); STGB(BUFU, 0, kb+256); STGB(BUFU, 64, kb+256); }, VM6);
      PHASE(0,        0, { STGA(2*BUFU, 0, kb+320); STGA(2*BUFU, 64, kb+320); STGA(2*BUFU, 128, kb+320); }, {});
      PHASE(0,        1, { STGA(2*BUFU, 192, kb+320); STGB(2*BUFU, 0, kb+320); STGB(2*BUFU, 64, kb+320); }, VM6);
      PHASE(BUFU,     0, { STGA(0, 0, kb+384); STGA(0, 64, kb+384); STGA(0, 128, kb+384); }, {});
      PHASE(BUFU,     1, { STGA(0, 192, kb+384); STGB(0, 0, kb+384); STGB(0, 64, kb+384); }, VM6);
      PHASE(2*BUFU,   0, { STGA(BUFU, 0, kb+448); STGA(BUFU, 64, kb+448); STGA(BUFU, 128, kb+448); }, {});
      PHASE(2*BUFU,   1, { STGA(BUFU, 192, kb+448); STGB(BUFU, 0, kb+448); STGB(BUFU, 64, kb+448); }, VM6);
      kb += 384;
    }

    PHASE(0,    0, {}, {});
    PHASE(0,    1, {}, VM0);
    PHASE(BUFU, 0, {}, {});
    PHASE(BUFU, 1, {}, {});

#pragma unroll
    for (int j = 0; j < 4; ++j) {
      int ng = rn0 + p * 128 + wn + j * 16 + l16;
      float bias = (ng < HID) ? bq[ng] : (ng < 2 * HID ? bk[ng - HID] : bv[ng - 2 * HID]);
      if (Vt != nullptr && ng >= 2 * HID) {
        const int vidx = ng - 2 * HID;
        const int bb = m0 >> 11;
        unsigned short* vrow = Vt
            + ((size_t)((bb * 16 + (vidx >> 7)) * 128 + (vidx & 127))) * SEQ
            + (m0 & 2047) + wm + quad * 4;
#pragma unroll
        for (int a = 0; a < 4; ++a) {
          ushort4 pk4;
          pk4.x = f2bf(acc[a][j][0] + bias);
          pk4.y = f2bf(acc[a][j][1] + bias);
          pk4.z = f2bf(acc[a][j][2] + bias);
          pk4.w = f2bf(acc[a][j][3] + bias);
          *(ushort4*)(vrow + a * 16) = pk4;
        }
      } else {
#pragma unroll
        for (int a = 0; a < 4; ++a)
#pragma unroll
          for (int r = 0; r < 4; ++r) {
            int mg = m0 + wm + a * 16 + quad * 4 + r;
            Cout[(size_t)mg * NQKV + ng] = f2bf(acc[a][j][r] + bias);
          }
      }
    }
  }
#undef STGA
#undef STGB
#undef PHASE
#undef VM6
#undef VM0
}

// ---------------- GEMM 2: out-proj, R11 loop + LDS-transposed coalesced epilogue ----------------
// Epilogue: stage the 256x128 fp32 block in LDS (stride 132 kills write-bank alias),
// then float4 Res-read + bias + float4 Out-write, fully coalesced (512B/instr/wave).
__global__ __launch_bounds__(512, 2) void gemm_out384_kernel(
    const unsigned short* __restrict__ Ctx, const unsigned short* __restrict__ Wdb,
    const float* __restrict__ bd, const float* __restrict__ Res,
    float* __restrict__ Out) {
  __shared__ __align__(16) unsigned short smem[BUF3];   // 144 KiB

  const int tid  = threadIdx.x;
  const int w    = tid >> 6;
  const int lane = tid & 63;
  const int l16  = lane & 15;
  const int quad = lane >> 4;
  const int wm   = (w & 3) * 64;
  const int wn   = (w >> 2) * 64;

  const int wg = blockIdx.x;
  const int sw = (wg & 7) * 32 + (wg >> 3);
  const int m0  = (sw & 15) * 256;
  const int rn0 = (sw >> 4) * 128;

  const int sr  = tid >> 3;
  const int scs = ((tid & 7) ^ (sr & 7)) * 8;
  const unsigned short* aBase = Ctx + (size_t)(m0 + sr) * HID + scs;
  const unsigned short* bBase = Wdb + (size_t)(rn0 + sr) * HID + scs;

#define STGA(UB, RB, KT)                                              \
  async16(aBase + (size_t)(RB) * HID + (KT),                          \
          (char*)smem + (UB) * 2 + (RB) * 128 + w * 1024)
#define STGB(UB, RB, KT)                                              \
  async16(bBase + (size_t)(RB) * HID + (KT),                          \
          (char*)smem + (UB) * 2 + 32768 + (RB) * 128 + w * 1024)

#define VM6  asm volatile("s_waitcnt vmcnt(6)" ::: "memory")
#define VM0  asm volatile("s_waitcnt vmcnt(0)" ::: "memory")

#define PHASE(UB, KK, STGBLK, WAITBLK)                                         \
  {                                                                            \
    const unsigned short* Ab = smem + (UB);                                    \
    const unsigned short* Bb = Ab + 16384;                                     \
    bf16x8 ta[4], tb[4];                                                       \
    ta[0] = frag(Ab, wm + l16, (KK) * 4 + quad);                               \
    _Pragma("unroll")                                                          \
    for (int j = 0; j < 4; ++j)  tb[j] = frag(Bb, wn + j * 16 + l16, (KK) * 4 + quad); \
    _Pragma("unroll")                                                          \
    for (int ii = 1; ii < 4; ++ii) ta[ii] = frag(Ab, wm + ii * 16 + l16, (KK) * 4 + quad); \
    STGBLK;                                                                    \
    __builtin_amdgcn_s_setprio(1);                                             \
    _Pragma("unroll")                                                          \
    for (int ii = 0; ii < 4; ++ii)                                             \
      _Pragma("unroll")                                                        \
      for (int j = 0; j < 4; ++j) mfma16(acc[ii][j], ta[ii], tb[j]);           \
    __builtin_amdgcn_s_setprio(0);                                             \
    asm volatile("s_waitcnt lgkmcnt(0)" ::: "memory");                         \
    WAITBLK;                                                                   \
    __builtin_amdgcn_s_barrier();                                              \
  }

  f32x4 acc[4][4];
  const f32x4 zero = {0.f, 0.f, 0.f, 0.f};
#pragma unroll
  for (int a = 0; a < 4; ++a)
#pragma unroll
    for (int j = 0; j < 4; ++j) acc[a][j] = zero;

  STGA(0, 0, 0);  STGA(0, 64, 0);  STGA(0, 128, 0);  STGA(0, 192, 0);
  STGB(0, 0, 0);  STGB(0, 64, 0);
  STGA(BUFU, 0, 64);  STGA(BUFU, 64, 64);  STGA(BUFU, 128, 64);  STGA(BUFU, 192, 64);
  STGB(BUFU, 0, 64);  STGB(BUFU, 64, 64);
  VM6;
  __builtin_amdgcn_s_barrier();

  int kb = 0;
  for (int g = 0; g < 5; ++g) {
    PHASE(0,        0, { STGA(2*BUFU, 0, kb+128); STGA(2*BUFU, 64, kb+128); STGA(2*BUFU, 128, kb+128); }, {});
    PHASE(0,        1, { STGA(2*BUFU, 192, kb+128); STGB(2*BUFU, 0, kb+128); STGB(2*BUFU, 64, kb+128); }, VM6);
    PHASE(BUFU,     0, { STGA(0, 0, kb+192); STGA(0, 64, kb+192); STGA(0, 128, kb+192); }, {});
    PHASE(BUFU,     1, { STGA(0, 192, kb+192); STGB(0, 0, kb+192); STGB(0, 64, kb+192); }, VM6);
    PHASE(2*BUFU,   0, { STGA(BUFU, 0, kb+256); STGA(BUFU, 64, kb+256); STGA(BUFU, 128, kb+256); }, {});
    PHASE(2*BUFU,   1, { STGA(BUFU, 192, kb+256); STGB(BUFU, 0, kb+256); STGB(BUFU, 64, kb+256); }, VM6);
    PHASE(0,        0, { STGA(2*BUFU, 0, kb+320); STGA(2*BUFU, 64, kb+320); STGA(2*BUFU, 128, kb+320); }, {});
    PHASE(0,        1, { STGA(2*BUFU, 192, kb+320); STGB(2*BUFU, 0, kb+320); STGB(2*BUFU, 64, kb+320); }, VM6);
    PHASE(BUFU,     0, { STGA(0, 0, kb+384); STGA(0, 64, kb+384); STGA(0, 128, kb+384); }, {});
    PHASE(BUFU,     1, { STGA(0, 192, kb+384); STGB(0, 0, kb+384); STGB(0, 64, kb+384); }, VM6);
    PHASE(2*BUFU,   0, { STGA(BUFU, 0, kb+448); STGA(BUFU, 64, kb+448); STGA(BUFU, 128, kb+448); }, {});
    PHASE(2*BUFU,   1, { STGA(BUFU, 192, kb+448); STGB(BUFU, 0, kb+448); STGB(BUFU, 64, kb+448); }, VM6);
    kb += 192 * 2;
  }

  PHASE(0,    0, {}, {});
  PHASE(0,    1, {}, VM0);
  PHASE(BUFU, 0, {}, {});
  PHASE(BUFU, 1, {}, {});

  // ---- LDS-transposed coalesced epilogue ----
  // (last PHASE drained all LDS reads per-wave before its barrier -> smem reusable)
  float* ep = (float*)smem;                   // 256 x 132 f32 = 135168 B < 147456
#pragma unroll
  for (int a = 0; a < 4; ++a)
#pragma unroll
    for (int j = 0; j < 4; ++j)
#pragma unroll
      for (int r = 0; r < 4; ++r)
        ep[(wm + a * 16 + quad * 4 + r) * 132 + wn + j * 16 + l16] = acc[a][j][r];
  __syncthreads();

  {
    const int row_t = tid >> 5;               // 0..15
    const int col4  = (tid & 31) * 4;         // 0..124
    float4 bias4 = *(const float4*)(bd + rn0 + col4);
#pragma unroll
    for (int s = 0; s < 16; ++s) {
      int row = s * 16 + row_t;
      size_t goff = (size_t)(m0 + row) * HID + rn0 + col4;
      const float* lp = ep + row * 132 + col4;
      float4 rv = *(const float4*)(Res + goff);
      float4 ov;
      ov.x = lp[0] + bias4.x + rv.x;
      ov.y = lp[1] + bias4.y + rv.y;
      ov.z = lp[2] + bias4.z + rv.z;
      ov.w = lp[3] + bias4.w + rv.w;
      *(float4*)(Out + goff) = ov;
    }
  }
#undef STGA
#undef STGB
#undef PHASE
#undef VM6
#undef VM0
}

// ---------------- V transpose (FALLBACK only, when ws too small for fused Vt) ----------------
__global__ __launch_bounds__(256) void vtrans_kernel(const unsigned short* __restrict__ QKV,
                                                     unsigned short* __restrict__ Vt) {
  __shared__ __align__(16) unsigned short T[64][72];
  const int s0 = blockIdx.x * 64, d0 = blockIdx.y * 64, bh = blockIdx.z;
  const int b = bh >> 4, h = bh & 15;
  const int tid = threadIdx.x;
#pragma unroll
  for (int i = 0; i < 2; ++i) {
    int idx = i * 256 + tid;
    int r = idx >> 3, ch = idx & 7;
    const unsigned short* g = QKV + ((size_t)b * SEQ + s0 + r) * NQKV + 2 * HID + h * HD + d0 + ch * 8;
    *(uint4*)(&T[r][ch * 8]) = *(const uint4*)g;
  }
  __syncthreads();
#pragma unroll
  for (int i = 0; i < 2; ++i) {
    int idx = i * 256 + tid;
    int d = idx >> 3, ch = idx & 7;
    unsigned short v[8];
#pragma unroll
    for (int x = 0; x < 8; ++x) v[x] = T[ch * 8 + x][d];
    unsigned short* g = Vt + ((size_t)bh * HD + d0 + d) * SEQ + s0 + ch * 8;
    *(uint4*)g = *(const uint4*)v;
  }
}

// ---------------- flash attention: 8-wave block, shared K/V staging (R11, unchanged) ----------------
__global__ __launch_bounds__(512, 2) void attn_kernel(
    const unsigned short* __restrict__ QKV, const unsigned short* __restrict__ Vt,
    const float* __restrict__ alibi, unsigned short* __restrict__ Ctx) {
  __shared__ __align__(16) char smem[73728];
  unsigned short* Ks0  = (unsigned short*)smem;
  unsigned short* Ks1  = (unsigned short*)(smem + 16384);
  unsigned short* Vts0 = (unsigned short*)(smem + 32768);
  unsigned short* Vts1 = (unsigned short*)(smem + 49152);
  float*          Alsf = (float*)(smem + 65536);
  unsigned short* Qs   = (unsigned short*)smem;   // alias: Q staging (64 KB over all 4 bufs)

  const int tid = threadIdx.x, w = tid >> 6, lane = tid & 63;
  const int l32 = lane & 31, h = lane >> 5;
  const int bid = blockIdx.x;
  const int t  = bid >> 3;
  const int q0 = (t & 7) * 256;
  const int bh = (bid & 7) + 8 * (t >> 3);
  const int b = bh >> 4, hh = bh & 15;
  const size_t rowbase = (size_t)b * SEQ;
  const float* ali = alibi + (size_t)bh * SEQ;
  const unsigned short* Vbh = Vt + (size_t)bh * HD * SEQ;

  {
    const unsigned short* qbase = QKV + (rowbase + q0) * NQKV + hh * HD;
#pragma unroll
    for (int i = 0; i < 8; ++i) {
      int slot = i * 512 + w * 64 + lane;
      int r = slot >> 4, c = (slot & 15) ^ (r & 15);
      async16(qbase + (size_t)r * NQKV + c * 8, (char*)Qs + (size_t)(i * 512 + w * 64) * 16);
    }
    async16((const char*)ali + (size_t)(w * 64 + lane) * 16, (char*)Alsf + (size_t)(w * 64) * 16);
  }
  __syncthreads();
  bf16x8 qf[8];
  {
    int qr = w * 32 + l32;
#pragma unroll
    for (int ks = 0; ks < 8; ++ks) {
      int c = (ks * 2 + h) ^ (qr & 15);
      qf[ks] = *(const bf16x8*)(Qs + (qr * 16 + c) * 8);
    }
  }

  f32x16 oacc[4];
  float l_acc = 0.f;
#pragma unroll
  for (int nb = 0; nb < 4; ++nb)
#pragma unroll
    for (int r = 0; r < 16; ++r) oacc[nb][r] = 0.f;

  __syncthreads();

#define STAGE_K(T, KD)                                                           \
  {                                                                              \
    const unsigned short* kbase = QKV + (rowbase + (size_t)(T) * 64) * NQKV + HID + hh * HD; \
    _Pragma("unroll")                                                            \
    for (int i = 0; i < 2; ++i) {                                                \
      int slot = i * 512 + w * 64 + lane;                                        \
      int r = slot >> 4, c = (slot & 15) ^ (r & 15);                             \
      async16(kbase + (size_t)r * NQKV + c * 8, (char*)(KD) + (size_t)(i * 512 + w * 64) * 16); \
    }                                                                            \
  }
#define STAGE_V(T, VD)                                                           \
  {                                                                              \
    const unsigned short* vbase = Vbh + (T) * 64;                                \
    _Pragma("unroll")                                                            \
    for (int i = 0; i < 2; ++i) {                                                \
      int slot = i * 512 + w * 64 + lane;                                        \
      int r = slot >> 3, c = (slot & 7) ^ (r & 7);                               \
      async16(vbase + (size_t)r * SEQ + c * 8, (char*)(VD) + (size_t)(i * 512 + w * 64) * 16); \
    }                                                                            \
  }

#define QKT(SACC, KBUF)                                                          \
  {                                                                              \
    _Pragma("unroll")                                                            \
    for (int mb = 0; mb < 2; ++mb)                                               \
      _Pragma("unroll")                                                          \
      for (int r = 0; r < 16; ++r) (SACC)[mb][r] = 0.f;                          \
    __builtin_amdgcn_s_setprio(1);                                               \
    _Pragma("unroll")                                                            \
    for (int ks = 0; ks < 8; ++ks)                                               \
      _Pragma("unroll")                                                          \
      for (int mb = 0; mb < 2; ++mb) {                                           \
        bf16x8 kf = *(const bf16x8*)((KBUF) + ((mb * 32 + l32) * 16 + ((ks * 2 + h) ^ (l32 & 15))) * 8); \
        (SACC)[mb] = __builtin_amdgcn_mfma_f32_32x32x16_bf16(kf, qf[ks], (SACC)[mb], 0, 0, 0); \
      }                                                                          \
    __builtin_amdgcn_s_setprio(0);                                               \
  }

#define SOFTMAX(SACC, KT, PFR)                                                   \
  {                                                                              \
    const float* alsk = Alsf + (KT) * 64 + 4 * h;                                \
    _Pragma("unroll")                                                            \
    for (int mb = 0; mb < 2; ++mb) {                                             \
      float p[16];                                                               \
      _Pragma("unroll")                                                          \
      for (int g = 0; g < 4; ++g) {                                              \
        float4 av = *(const float4*)(alsk + mb * 32 + g * 8);                    \
        p[g * 4 + 0] = __builtin_amdgcn_exp2f((SACC)[mb][g * 4 + 0] * SCALE_L2 + av.x * LOG2E); \
        p[g * 4 + 1] = __builtin_amdgcn_exp2f((SACC)[mb][g * 4 + 1] * SCALE_L2 + av.y * LOG2E); \
        p[g * 4 + 2] = __builtin_amdgcn_exp2f((SACC)[mb][g * 4 + 2] * SCALE_L2 + av.z * LOG2E); \
        p[g * 4 + 3] = __builtin_amdgcn_exp2f((SACC)[mb][g * 4 + 3] * SCALE_L2 + av.w * LOG2E); \
        l_acc += (p[g * 4 + 0] + p[g * 4 + 1]) + (p[g * 4 + 2] + p[g * 4 + 3]);  \
      }                                                                          \
      unsigned c0 = pkbf(p[0],  p[1]),  c1 = pkbf(p[2],  p[3]);                  \
      unsigned c2 = pkbf(p[4],  p[5]),  c3 = pkbf(p[6],  p[7]);                  \
      unsigned c4 = pkbf(p[8],  p[9]),  c5 = pkbf(p[10], p[11]);                 \
      unsigned c6 = pkbf(p[12], p[13]), c7 = pkbf(p[14], p[15]);                 \
      pl32swap(c0, c2);  pl32swap(c1, c3);                                       \
      pl32swap(c4, c6);  pl32swap(c5, c7);                                       \
      uint4 f0; f0.x = c0; f0.y = c1; f0.z = c2; f0.w = c3;                      \
      uint4 f1; f1.x = c4; f1.y = c5; f1.z = c6; f1.w = c7;                      \
      (PFR)[mb * 2 + 0] = __builtin_bit_cast(bf16x8, f0);                        \
      (PFR)[mb * 2 + 1] = __builtin_bit_cast(bf16x8, f1);                        \
    }                                                                            \
  }

#define PVOP(PFR, VBUF)                                                          \
  {                                                                              \
    __builtin_amdgcn_s_setprio(1);                                               \
    _Pragma("unroll")                                                            \
    for (int ks2 = 0; ks2 < 4; ++ks2) {                                          \
      bf16x8 pf = (PFR)[ks2];                                                    \
      _Pragma("unroll")                                                          \
      for (int nb = 0; nb < 4; ++nb) {                                           \
        bf16x8 vf = *(const bf16x8*)((VBUF) + ((nb * 32 + l32) * 8 + ((ks2 * 2 + h) ^ (l32 & 7))) * 8); \
        oacc[nb] = __builtin_amdgcn_mfma_f32_32x32x16_bf16(pf, vf, oacc[nb], 0, 0, 0); \
      }                                                                          \
    }                                                                            \
    __builtin_amdgcn_s_setprio(0);                                               \
  }

  STAGE_K(0, Ks0);  STAGE_V(0, Vts0);
  STAGE_K(1, Ks1);  STAGE_V(1, Vts1);
  asm volatile("s_waitcnt vmcnt(4)" ::: "memory");
  __builtin_amdgcn_s_barrier();

  f32x16 sA[2], sB[2];
  QKT(sA, Ks0);
  asm volatile("s_waitcnt lgkmcnt(0)" ::: "memory");
  __builtin_amdgcn_s_barrier();

  for (int kt = 0; kt < 30; kt += 2) {
    STAGE_K(kt + 2, Ks0);
    asm volatile("s_waitcnt vmcnt(4)" ::: "memory");
    QKT(sB, Ks1);
    { bf16x8 pfr[4]; SOFTMAX(sA, kt, pfr); PVOP(pfr, Vts0); }
    asm volatile("s_waitcnt lgkmcnt(0)" ::: "memory");
    __builtin_amdgcn_s_barrier();
    STAGE_V(kt + 2, Vts0);
    STAGE_K(kt + 3, Ks1);
    asm volatile("s_waitcnt vmcnt(4)" ::: "memory");
    QKT(sA, Ks0);
    { bf16x8 pfr[4]; SOFTMAX(sB, kt + 1, pfr); PVOP(pfr, Vts1); }
    asm volatile("s_waitcnt lgkmcnt(0)" ::: "memory");
    __builtin_amdgcn_s_barrier();
    STAGE_V(kt + 3, Vts1);
  }

  asm volatile("s_waitcnt vmcnt(2)" ::: "memory");
  QKT(sB, Ks1);
  { bf16x8 pfr[4]; SOFTMAX(sA, 30, pfr); PVOP(pfr, Vts0); }
  asm volatile("s_waitcnt lgkmcnt(0) vmcnt(0)" ::: "memory");
  __builtin_amdgcn_s_barrier();
  { bf16x8 pfr[4]; SOFTMAX(sB, 31, pfr); PVOP(pfr, Vts1); }
  asm volatile("s_waitcnt lgkmcnt(0)" ::: "memory");

#undef STAGE_K
#undef STAGE_V
#undef QKT
#undef SOFTMAX
#undef PVOP

  float lf = l_acc + __shfl_xor(l_acc, 32, 64);
  float rinv[16];
#pragma unroll
  for (int reg = 0; reg < 16; ++reg) {
    int row = (reg & 3) + 8 * (reg >> 2) + 4 * h;
    rinv[reg] = 1.0f / __shfl(lf, row, 64);
  }

#pragma unroll
  for (int nb = 0; nb < 4; ++nb)
#pragma unroll
    for (int reg = 0; reg < 16; ++reg) {
      int row = (reg & 3) + 8 * (reg >> 2) + 4 * h;
      size_t qg = rowbase + q0 + w * 32 + row;
      Ctx[qg * HID + hh * HD + nb * 32 + l32] = f2bf(oacc[nb][reg] * rinv[reg]);
    }
}

// ---------------- launch ----------------
extern "C" void kernel_launch(void* const* d_in, const int* in_sizes, int n_in,
                              void* d_out, int out_size, void* d_ws, size_t ws_size,
                              hipStream_t stream) {
  const float* hidden   = (const float*)d_in[0];
  const float* residual = (const float*)d_in[1];
  const float* alibi    = (const float*)d_in[2];
  const float* Wq = (const float*)d_in[3];
  const float* bq = (const float*)d_in[4];
  const float* Wk = (const float*)d_in[5];
  const float* bk = (const float*)d_in[6];
  const float* Wv = (const float*)d_in[7];
  const float* bv = (const float*)d_in[8];
  const float* Wd = (const float*)d_in[9];
  const float* bd = (const float*)d_in[10];
  float* out = (float*)d_out;

  unsigned short* Xb    = (unsigned short*)d_ws;                    // 4096*2048
  unsigned short* Wqkvb = Xb + (size_t)MROWS * HID;                 // 6144*2048
  unsigned short* Wdb   = Wqkvb + (size_t)NQKV * HID;               // 2048*2048
  unsigned short* QKVb  = Wdb + (size_t)HID * HID;                  // 4096*6144
  unsigned short* Ctxb  = QKVb + (size_t)MROWS * NQKV;              // 4096*2048
  unsigned short* VtF   = Ctxb + (size_t)MROWS * HID;               // 32*128*2048 (fused path)

  const size_t needU = (size_t)MROWS * HID + (size_t)NQKV * HID + (size_t)HID * HID
                     + (size_t)MROWS * NQKV + (size_t)MROWS * HID
                     + (size_t)BATCH * NHEAD * HD * SEQ;
  const bool fused = ws_size >= needU * sizeof(unsigned short);

  const int nTot = (MROWS * HID + 4 * HID * HID) / 4 / 256;   // 24576 blocks, exact
  cvt_all_kernel<<<nTot, 256, 0, stream>>>(hidden, Wq, Wk, Wv, Wd, Xb);

  if (fused) {
    gemm_qkv384_kernel<<<256, 512, 0, stream>>>(Xb, Wqkvb, bq, bk, bv, QKVb, VtF);
    attn_kernel<<<256, 512, 0, stream>>>(QKVb, VtF, alibi, Ctxb);
  } else {
    unsigned short* Vtb = Wqkvb;   // weights dead after gemm_qkv in this path
    gemm_qkv384_kernel<<<256, 512, 0, stream>>>(Xb, Wqkvb, bq, bk, bv, QKVb, nullptr);
    vtrans_kernel<<<dim3(SEQ / 64, HD / 64, BATCH * NHEAD), 256, 0, stream>>>(QKVb, Vtb);
    attn_kernel<<<256, 512, 0, stream>>>(QKVb, Vtb, alibi, Ctxb);
  }
  gemm_out384_kernel<<<256, 512, 0, stream>>>(Ctxb, Wdb, bd, residual, out);
}